// Round 17
// baseline (115.654 us; speedup 1.0000x reference)
//
#include <hip/hip_runtime.h>
#include <stdint.h>

typedef unsigned short ushort_t;
typedef __bf16 bf16x4 __attribute__((ext_vector_type(4)));
typedef __bf16 bf16x8 __attribute__((ext_vector_type(8)));
typedef float f32x4 __attribute__((ext_vector_type(4)));
typedef float f32x16 __attribute__((ext_vector_type(16)));
typedef unsigned short us8 __attribute__((ext_vector_type(8)));
typedef unsigned short us4v __attribute__((ext_vector_type(4)));

__device__ __forceinline__ float bf2f(ushort_t u) {
  union { uint32_t u; float f; } v; v.u = ((uint32_t)u) << 16; return v.f;
}
__device__ __forceinline__ ushort_t f2bf(float f) {
  union { float f; uint32_t u; } v; v.f = f;
  uint32_t u = v.u;
  uint32_t r = (u + 0x7FFFu + ((u >> 16) & 1u)) >> 16;  // RNE
  return (ushort_t)r;
}
// hardware packed bf16 convert (RNE): dst = {lo: bf16(a), hi: bf16(b)}
__device__ __forceinline__ uint32_t cvtpk(float a, float b) {
  uint32_t r;
  asm("v_cvt_pk_bf16_f32 %0, %1, %2" : "=v"(r) : "v"(a), "v"(b));
  return r;
}
__device__ __forceinline__ void gload_lds16(const void* g, void* l) {
  __builtin_amdgcn_global_load_lds(
      (const __attribute__((address_space(1))) void*)g,
      (__attribute__((address_space(3))) void*)l, 16, 0, 0);
}
// ds_read_b64_tr_b16 (cross-lane transpose): 16-lane group, lane reads its
// own qword at base+(l&15)*8; delivers column (l&15) of the [4kv][16d] subtile.
__device__ __forceinline__ void tr2(const ushort_t* p, bf16x4& lo, bf16x4& hi) {
  asm volatile("ds_read_b64_tr_b16 %0, %2\n\t"
               "ds_read_b64_tr_b16 %1, %2 offset:128"
               : "=&v"(lo), "=&v"(hi)
               : "v"((const __attribute__((address_space(3))) ushort_t*)p));
}

template <typename T> __device__ __forceinline__ T to_out(float f);
template <> __device__ __forceinline__ ushort_t to_out<ushort_t>(float f) { return f2bf(f); }
template <> __device__ __forceinline__ float to_out<float>(float f) { return f; }

#define SCQ 0.1803368801111204f   /* 0.125 * log2(e) */
#define VMCNT(n) asm volatile("s_waitcnt vmcnt(" #n ")" ::: "memory")

// ---------------------------------------------------------------------------
// fp32 -> bf16 convert, three inputs, static block partition
// ---------------------------------------------------------------------------
__global__ void f2b3_kernel(const float* __restrict__ a, ushort_t* __restrict__ ao,
                            const float* __restrict__ b, ushort_t* __restrict__ bo,
                            const float* __restrict__ c, ushort_t* __restrict__ co) {
  int blk = blockIdx.x;
  const float* src; ushort_t* dst; int n4, b0, nb;
  if (blk < 1024)      { src = a; dst = ao; n4 = 1048576; b0 = blk;        nb = 1024; }
  else if (blk < 1792) { src = b; dst = bo; n4 = 786432;  b0 = blk - 1024; nb = 768; }
  else                 { src = c; dst = co; n4 = 262144;  b0 = blk - 1792; nb = 256; }
  for (int i = b0 * 256 + threadIdx.x; i < n4; i += nb * 256) {
    float4 v = ((const float4*)src)[i];
    us4v o;
    o[0] = f2bf(v.x); o[1] = f2bf(v.y); o[2] = f2bf(v.z); o[3] = f2bf(v.w);
    ((us4v*)dst)[i] = o;
  }
}

// ---------------------------------------------------------------------------
// QKV GEMM, 256^2 tile, counted-vmcnt 4-phase pipeline (T3+T4+T5).
// C[4096][3072] = A[4096][1024] @ W[3072][1024]^T, Q cols (<1024) scaled SCQ.
// 512 thr = 8 waves (2M x 4N), per-wave C = 128x64 (acc[8][4] f32x4).
// LDS = ring of 4 K-half slots; slot = A[256][32] + B[256][32] = 32 KB.
// Half h: ktile = h>>1, khalf = h&1, slot h&3. Staging runs 2 K-tiles ahead;
// vmcnt(8) at phase 1/3 ends only (4/0 at tail) -- loads stay in flight
// across barriers. Chunk-XOR swizzle (proven 0-conflict) on 64B rows.
// ---------------------------------------------------------------------------
__global__ __launch_bounds__(512, 1) void gemm256_qkv(
    const ushort_t* __restrict__ A, const ushort_t* __restrict__ W,
    ushort_t* __restrict__ C)
{
  __shared__ ushort_t Lds[4 * 16384];   // 4 slots x 32 KB

  const int t = threadIdx.x;
  const int w = t >> 6, lane = t & 63;
  const int lg = lane >> 4, lc = lane & 15;
  const int wr = w >> 2, wc = w & 3;    // 2M x 4N wave grid

  // T1 XCD swizzle over 192 blocks (192 % 8 == 0), NX = 12
  const int o = blockIdx.x;
  const int id = (o & 7) * 24 + (o >> 3);
  const int rowbase = (id / 12) * 256;
  const int colbase = (id % 12) * 256;

  // stage one matrix-half of half-tile h (2 x global_load_lds, linear dest)
  auto stageA = [&](int h) {
    int kt2 = h >> 1, kh = h & 1;
    char* db = (char*)Lds + (h & 3) * 32768;
#pragma unroll
    for (int g = 0; g < 2; ++g) {
      int r = (t >> 2) + g * 128;
      int cs = (t & 3) ^ (r & 3);
      gload_lds16(A + (size_t)(rowbase + r) * 1024 + kt2 * 64 + kh * 32 + cs * 8,
                  db + g * 8192 + t * 16);
    }
  };
  auto stageB = [&](int h) {
    int kt2 = h >> 1, kh = h & 1;
    char* db = (char*)Lds + (h & 3) * 32768 + 16384;
#pragma unroll
    for (int g = 0; g < 2; ++g) {
      int r = (t >> 2) + g * 128;
      int cs = (t & 3) ^ (r & 3);
      gload_lds16(W + (size_t)(colbase + r) * 1024 + kt2 * 64 + kh * 32 + cs * 8,
                  db + g * 8192 + t * 16);
    }
  };

  f32x4 acc[8][4] = {};

  // ---- prologue: stage h0, h1, h2 (12 loads); wait h0 (outstanding 8) ----
  stageA(0); stageB(0);
  stageA(1); stageB(1);
  stageA(2); stageB(2);
  VMCNT(8);
  __builtin_amdgcn_s_barrier();

  for (int kt = 0; kt < 16; ++kt) {
    const int s0 = (2 * kt) & 3;             // even slot (ks0), s0+1 = ks1
    const ushort_t* A0p = Lds + s0 * 16384;
    const ushort_t* B0p = A0p + 8192;
    const ushort_t* A1p = Lds + (s0 + 1) * 16384;
    const ushort_t* B1p = A1p + 8192;

    bf16x8 bf[4], af[4];

    // ===== phase 0: slot s0, B n0-3 + A m0-3; stage A(h=2kt+3) =====
#pragma unroll
    for (int n = 0; n < 4; ++n) {
      int row = wc * 64 + n * 16 + lc;
      bf[n] = *(const bf16x8*)((const char*)B0p + row * 64 +
                               ((lg ^ (row & 3)) << 4));
    }
#pragma unroll
    for (int m = 0; m < 4; ++m) {
      int row = wr * 128 + m * 16 + lc;
      af[m] = *(const bf16x8*)((const char*)A0p + row * 64 +
                               ((lg ^ (row & 3)) << 4));
    }
    if (kt < 15) stageA(2 * kt + 3);
    __builtin_amdgcn_s_barrier();
    __builtin_amdgcn_s_setprio(1);
#pragma unroll
    for (int m = 0; m < 4; ++m)
#pragma unroll
      for (int n = 0; n < 4; ++n)
        acc[m][n] = __builtin_amdgcn_mfma_f32_16x16x32_bf16(af[m], bf[n],
                                                            acc[m][n], 0, 0, 0);
    __builtin_amdgcn_s_setprio(0);
    __builtin_amdgcn_s_barrier();

    // ===== phase 1: slot s0, A m4-7 (bf held); stage B(h=2kt+3) =====
#pragma unroll
    for (int m = 0; m < 4; ++m) {
      int row = wr * 128 + (m + 4) * 16 + lc;
      af[m] = *(const bf16x8*)((const char*)A0p + row * 64 +
                               ((lg ^ (row & 3)) << 4));
    }
    if (kt < 15) stageB(2 * kt + 3);
    __builtin_amdgcn_s_barrier();
    __builtin_amdgcn_s_setprio(1);
#pragma unroll
    for (int m = 0; m < 4; ++m)
#pragma unroll
      for (int n = 0; n < 4; ++n)
        acc[m + 4][n] = __builtin_amdgcn_mfma_f32_16x16x32_bf16(af[m], bf[n],
                                                                acc[m + 4][n], 0, 0, 0);
    __builtin_amdgcn_s_setprio(0);
    if (kt < 15) { VMCNT(8); } else { VMCNT(0); }   // slot s0+1 ready
    __builtin_amdgcn_s_barrier();

    // ===== phase 2: slot s0+1 (ks1), B + A m0-3; stage A(h=2kt+4) =====
#pragma unroll
    for (int n = 0; n < 4; ++n) {
      int row = wc * 64 + n * 16 + lc;
      bf[n] = *(const bf16x8*)((const char*)B1p + row * 64 +
                               ((lg ^ (row & 3)) << 4));
    }
#pragma unroll
    for (int m = 0; m < 4; ++m) {
      int row = wr * 128 + m * 16 + lc;
      af[m] = *(const bf16x8*)((const char*)A1p + row * 64 +
                               ((lg ^ (row & 3)) << 4));
    }
    if (kt < 14) stageA(2 * kt + 4);
    __builtin_amdgcn_s_barrier();
    __builtin_amdgcn_s_setprio(1);
#pragma unroll
    for (int m = 0; m < 4; ++m)
#pragma unroll
      for (int n = 0; n < 4; ++n)
        acc[m][n] = __builtin_amdgcn_mfma_f32_16x16x32_bf16(af[m], bf[n],
                                                            acc[m][n], 0, 0, 0);
    __builtin_amdgcn_s_setprio(0);
    __builtin_amdgcn_s_barrier();

    // ===== phase 3: slot s0+1, A m4-7; stage B(h=2kt+4) =====
#pragma unroll
    for (int m = 0; m < 4; ++m) {
      int row = wr * 128 + (m + 4) * 16 + lc;
      af[m] = *(const bf16x8*)((const char*)A1p + row * 64 +
                               ((lg ^ (row & 3)) << 4));
    }
    if (kt < 14) stageB(2 * kt + 4);
    __builtin_amdgcn_s_barrier();
    __builtin_amdgcn_s_setprio(1);
#pragma unroll
    for (int m = 0; m < 4; ++m)
#pragma unroll
      for (int n = 0; n < 4; ++n)
        acc[m + 4][n] = __builtin_amdgcn_mfma_f32_16x16x32_bf16(af[m], bf[n],
                                                                acc[m + 4][n], 0, 0, 0);
    __builtin_amdgcn_s_setprio(0);
    if (kt < 14)      { VMCNT(8); __builtin_amdgcn_s_barrier(); }
    else if (kt == 14){ VMCNT(4); __builtin_amdgcn_s_barrier(); }
    // kt == 15: loop ends, no further LDS reads
  }

  // ---- epilogue: Q-prescale cols < 1024, bf16 out ----
#pragma unroll
  for (int m = 0; m < 8; ++m) {
    int r0 = rowbase + wr * 128 + m * 16 + lg * 4;
#pragma unroll
    for (int n = 0; n < 4; ++n) {
      int c0 = colbase + wc * 64 + n * 16 + lc;
      float qs = (c0 < 1024) ? SCQ : 1.f;
#pragma unroll
      for (int j = 0; j < 4; ++j)
        C[(size_t)(r0 + j) * 3072 + c0] = f2bf(acc[m][n][j] * qs);
    }
  }
}

// ---------------------------------------------------------------------------
// GEMM (proj): C[M][N] = A[M][K] @ W[N][K]^T (+bias) -- proven m97 structure.
// ---------------------------------------------------------------------------
template<bool BIAS, typename OT, bool SCALEQ>
__global__ __launch_bounds__(256, 2) void gemm_bt(
    const ushort_t* __restrict__ A, const ushort_t* __restrict__ W,
    const float* __restrict__ bias, OT* __restrict__ C,
    int M, int N, int K)
{
  __shared__ ushort_t As[128 * 64];
  __shared__ ushort_t Bs[128 * 64];
  const int t = threadIdx.x;
  const int w = t >> 6, lane = t & 63;
  const int lg = lane >> 4, lc = lane & 15;

  const int NX = N >> 7;
  const int nwg = gridDim.x;
  const int o = blockIdx.x;
  const int id = (o & 7) * (nwg >> 3) + (o >> 3);
  const int rowbase = (id / NX) * 128;
  const int colbase = (id % NX) * 128;
  const int wr = (w >> 1) * 64, wc = (w & 1) * 64;

  f32x4 acc[4][4] = {};
  const int nkt = K >> 6;

  for (int kt = 0; kt < nkt; ++kt) {
#pragma unroll
    for (int i = 0; i < 4; ++i) {
      int off = (i * 256 + t) * 16;
      int row = off >> 7;
      int cb  = off & 127;
      int ec  = cb ^ ((row & 7) << 4);
      gload_lds16(A + (size_t)(rowbase + row) * K + kt * 64 + (ec >> 1),
                  (char*)As + off);
      gload_lds16(W + (size_t)(colbase + row) * K + kt * 64 + (ec >> 1),
                  (char*)Bs + off);
    }
    __syncthreads();
#pragma unroll
    for (int kk = 0; kk < 2; ++kk) {
      bf16x8 af[4], bf[4];
#pragma unroll
      for (int m = 0; m < 4; ++m) {
        int row = wr + m * 16 + lc;
        int kb  = (lg * 16 + kk * 64) ^ ((row & 7) << 4);
        af[m] = *(const bf16x8*)((const char*)As + row * 128 + kb);
        int col = wc + m * 16 + lc;
        int kb2 = (lg * 16 + kk * 64) ^ ((col & 7) << 4);
        bf[m] = *(const bf16x8*)((const char*)Bs + col * 128 + kb2);
      }
#pragma unroll
      for (int m = 0; m < 4; ++m)
#pragma unroll
        for (int n = 0; n < 4; ++n)
          acc[m][n] = __builtin_amdgcn_mfma_f32_16x16x32_bf16(af[m], bf[n],
                                                              acc[m][n], 0, 0, 0);
    }
    __syncthreads();
  }

#pragma unroll
  for (int m = 0; m < 4; ++m) {
    int r0 = rowbase + wr + m * 16 + lg * 4;
#pragma unroll
    for (int n = 0; n < 4; ++n) {
      int c0 = colbase + wc + n * 16 + lc;
      float bv = 0.f;
      if (BIAS) bv = bias[c0];
      float qs = 1.f;
      if (SCALEQ) qs = (c0 < 1024) ? SCQ : 1.f;
#pragma unroll
      for (int j = 0; j < 4; ++j)
        C[(size_t)(r0 + j) * N + c0] = to_out<OT>(acc[m][n][j] * qs + bv);
    }
  }
}

// ---------------------------------------------------------------------------
// Flash attention (r14, verified best): 8 waves/512 thr, q-tile 256,
// KV-split(2), 16 iters kv64, max-free softmax (Q pre-scaled by SCQ),
// cvt_pk P-pack, permlane32_swap, tr_read V, MFMA-ones l row-sum.
// ---------------------------------------------------------------------------
__global__ __launch_bounds__(512, 4) void attn_fwd(
    const ushort_t* __restrict__ qkv, ushort_t* __restrict__ o1,
    ushort_t* __restrict__ o2, float* __restrict__ lbuf)
{
  __shared__ ushort_t Ks[2][64 * 64];
  __shared__ ushort_t Vs[2][64 * 64];

  const int t = threadIdx.x, w = t >> 6, lane = t & 63;
  const int l31 = lane & 31, hi = lane >> 5;
  const int lc = lane & 15;

  const int d = blockIdx.x;
  const int qt = (d >> 3) & 7;
  const int bhs = (d & 7) * 8 + (d >> 6);
  const int bh = bhs >> 1, split = bhs & 1;
  const int b = bh >> 4, h = bh & 15;

  const ushort_t* Qg = qkv + (size_t)(b * 2048) * 3072 + h * 64;
  const ushort_t* Kg = Qg + 1024 + (size_t)split * 1024 * 3072;
  const ushort_t* Vg = Qg + 2048 + (size_t)split * 1024 * 3072;

  auto stage_k = [&](ushort_t* Kd, int kt) {
    int off = t * 16;
    int row = off >> 7;
    int cb  = off & 127;
    int ec  = cb ^ ((row & 7) << 4);
    gload_lds16(Kg + (size_t)(kt * 64 + row) * 3072 + (ec >> 1),
                (char*)Kd + off);
  };
  const int vr  = t >> 3;
  const int vc0 = (t & 7) * 8;
  const int vdst = (vc0 >> 4) * 2048 + (vr >> 2) * 128 + (vr & 3) * 32 +
                   (vc0 & 8) * 2;

  const ushort_t* qrow_p = Qg + (size_t)(qt * 256 + w * 32 + l31) * 3072;
  bf16x8 qf[4];
#pragma unroll
  for (int kk = 0; kk < 4; ++kk)
    qf[kk] = *(const bf16x8*)(qrow_p + kk * 16 + hi * 8);

  bf16x8 ones;
#pragma unroll
  for (int i = 0; i < 8; ++i) ones[i] = (__bf16)1.0f;

  stage_k(Ks[0], 0);
  {
    us8 v = *(const us8*)(Vg + (size_t)vr * 3072 + vc0);
    *(us8*)((char*)Vs[0] + vdst) = v;
  }
  __syncthreads();

  f32x16 oacc0 = {}, oacc1 = {}, lacc = {};
  const int m16 = (lane >> 4) & 1;

  int cur = 0;
  for (int kt = 0; kt < 16; ++kt) {
    us8 vnext;
    if (kt < 15) {
      stage_k(Ks[cur ^ 1], kt + 1);
      vnext = *(const us8*)(Vg + (size_t)((kt + 1) * 64 + vr) * 3072 + vc0);
    }

    const ushort_t* Kc = Ks[cur];
    f32x16 s0 = {}, s1 = {};
    __builtin_amdgcn_s_setprio(1);
#pragma unroll
    for (int kk = 0; kk < 4; ++kk) {
      int cbyte = (kk * 32 + hi * 16);
      int r0 = l31, r1 = 32 + l31;
      bf16x8 kf0 = *(const bf16x8*)((const char*)Kc + r0 * 128 +
                                    (cbyte ^ ((r0 & 7) << 4)));
      bf16x8 kf1 = *(const bf16x8*)((const char*)Kc + r1 * 128 +
                                    (cbyte ^ ((r1 & 7) << 4)));
      s0 = __builtin_amdgcn_mfma_f32_32x32x16_bf16(kf0, qf[kk], s0, 0, 0, 0);
      s1 = __builtin_amdgcn_mfma_f32_32x32x16_bf16(kf1, qf[kk], s1, 0, 0, 0);
    }
    __builtin_amdgcn_s_setprio(0);

#pragma unroll
    for (int i = 0; i < 16; ++i) {
      s0[i] = __builtin_amdgcn_exp2f(s0[i]);
      s1[i] = __builtin_amdgcn_exp2f(s1[i]);
    }

    uint32_t pk0[8], pk1[8];
#pragma unroll
    for (int j = 0; j < 8; ++j) {
      pk0[j] = cvtpk(s0[2 * j], s0[2 * j + 1]);
      pk1[j] = cvtpk(s1[2 * j], s1[2 * j + 1]);
    }

    if (kt < 15)
      *(us8*)((char*)Vs[cur ^ 1] + vdst) = vnext;

    const ushort_t* Vc = Vs[cur];
    bf16x8 pa[4], vf[4][2];
#pragma unroll
    for (int ks = 0; ks < 4; ++ks) {
      int j0 = 4 * (ks & 1);
      uint32_t x0 = (ks < 2) ? pk0[j0]     : pk1[j0];
      uint32_t x1 = (ks < 2) ? pk0[j0 + 1] : pk1[j0 + 1];
      uint32_t y0 = (ks < 2) ? pk0[j0 + 2] : pk1[j0 + 2];
      uint32_t y1 = (ks < 2) ? pk0[j0 + 3] : pk1[j0 + 3];
      asm volatile("v_permlane32_swap_b32 %0, %1" : "+v"(x0), "+v"(y0));
      asm volatile("v_permlane32_swap_b32 %0, %1" : "+v"(x1), "+v"(y1));
      union { uint32_t du[4]; bf16x8 v; } U;
      U.du[0] = x0; U.du[1] = x1; U.du[2] = y0; U.du[3] = y1;
      pa[ks] = U.v;
#pragma unroll
      for (int nd = 0; nd < 2; ++nd) {
        bf16x4 lo, hh;
        tr2(Vc + (nd * 2 + m16) * 1024 + (4 * ks + 2 * hi) * 64 + lc * 4, lo, hh);
        vf[ks][nd] = __builtin_shufflevector(lo, hh, 0, 1, 2, 3, 4, 5, 6, 7);
      }
    }
    asm volatile("s_waitcnt lgkmcnt(0)" ::: "memory");  // rule #18
    __builtin_amdgcn_sched_barrier(0);
    __builtin_amdgcn_s_setprio(1);
#pragma unroll
    for (int ks = 0; ks < 4; ++ks) {
      oacc0 = __builtin_amdgcn_mfma_f32_32x32x16_bf16(pa[ks], vf[ks][0], oacc0, 0, 0, 0);
      oacc1 = __builtin_amdgcn_mfma_f32_32x32x16_bf16(pa[ks], vf[ks][1], oacc1, 0, 0, 0);
      lacc  = __builtin_amdgcn_mfma_f32_32x32x16_bf16(pa[ks], ones, lacc, 0, 0, 0);
    }
    __builtin_amdgcn_s_setprio(0);

    __syncthreads();
    cur ^= 1;
  }

  ushort_t* op = split ? o2 : o1;
  const int qrow0 = qt * 256 + w * 32;
#pragma unroll
  for (int r = 0; r < 16; ++r) {
    int crow = (r & 3) + 8 * (r >> 2) + 4 * hi;
    size_t base = ((size_t)(b * 2048 + qrow0 + crow)) * 1024 + h * 64 + l31;
    op[base]      = f2bf(oacc0[r]);
    op[base + 32] = f2bf(oacc1[r]);
  }
  if (l31 == 0) {
#pragma unroll
    for (int r = 0; r < 16; ++r) {
      int crow = (r & 3) + 8 * (r >> 2) + 4 * hi;
      lbuf[(size_t)split * 65536 +
           (size_t)(b * 2048 + qrow0 + crow) * 16 + h] = lacc[r];
    }
  }
}

// ---------------------------------------------------------------------------
// merge: o1 = (o1 + o2) / (l1 + l2), in-place (max-free partials).
// ---------------------------------------------------------------------------
__global__ void merge_kernel(ushort_t* __restrict__ o1,
                             const ushort_t* __restrict__ o2,
                             const float* __restrict__ lbuf) {
  int i = blockIdx.x * blockDim.x + threadIdx.x;
  int row = i >> 7;
  int col = (i & 127) * 8;
  int h = col >> 6;
  float l1 = lbuf[(size_t)row * 16 + h];
  float l2 = lbuf[65536 + (size_t)row * 16 + h];
  float inv = 1.f / (l1 + l2);
  us8 v1 = ((const us8*)o1)[i];
  us8 v2 = ((const us8*)o2)[i];
  us8 o;
#pragma unroll
  for (int j = 0; j < 8; ++j)
    o[j] = f2bf((bf2f(v1[j]) + bf2f(v2[j])) * inv);
  ((us8*)o1)[i] = o;
}

// ---------------------------------------------------------------------------
extern "C" void kernel_launch(void* const* d_in, const int* in_sizes, int n_in,
                              void* d_out, int out_size, void* d_ws, size_t ws_size,
                              hipStream_t stream) {
  const float* x     = (const float*)d_in[0];   // [2,2048,1024] fp32
  const float* Wqkv  = (const float*)d_in[1];   // [3072,1024] fp32
  const float* Wproj = (const float*)d_in[2];   // [1024,1024] fp32
  const float* bproj = (const float*)d_in[3];   // [1024] fp32
  float* out = (float*)d_out;                   // [4096,1024] fp32

  ushort_t* qkv   = (ushort_t*)d_ws;                    // [4096,3072] bf16
  ushort_t* o1    = qkv   + (size_t)4096 * 3072;        // [4096,1024] bf16 (O1/merged)
  ushort_t* xb    = o1    + (size_t)4096 * 1024;        // [4096,1024] bf16 (x, then O2)
  ushort_t* wqb   = xb    + (size_t)4096 * 1024;        // [3072,1024] bf16
  ushort_t* wpb   = wqb   + (size_t)3072 * 1024;        // [1024,1024] bf16
  float*    lbuf  = (float*)(wpb + (size_t)1024 * 1024); // [2][4096][16] float

  dim3 blk(256);
  f2b3_kernel<<<2048, blk, 0, stream>>>(x, xb, Wqkv, wqb, Wproj, wpb);

  gemm256_qkv<<<192, dim3(512), 0, stream>>>(xb, wqb, qkv);
  attn_fwd<<<dim3(512), dim3(512), 0, stream>>>(qkv, o1, xb, lbuf);
  merge_kernel<<<2048, blk, 0, stream>>>(o1, xb, lbuf);
  gemm_bt<true, float, false><<<256, blk, 0, stream>>>(
      o1, wpb, bproj, out, 4096, 1024, 1024);
}

// Round 18
// 109.578 us; speedup vs baseline: 1.0554x; 1.0554x over previous
//
#include <hip/hip_runtime.h>
#include <stdint.h>

typedef unsigned short ushort_t;
typedef __bf16 bf16x4 __attribute__((ext_vector_type(4)));
typedef __bf16 bf16x8 __attribute__((ext_vector_type(8)));
typedef float f32x4 __attribute__((ext_vector_type(4)));
typedef float f32x16 __attribute__((ext_vector_type(16)));
typedef unsigned short us8 __attribute__((ext_vector_type(8)));

__device__ __forceinline__ float bf2f(ushort_t u) {
  union { uint32_t u; float f; } v; v.u = ((uint32_t)u) << 16; return v.f;
}
__device__ __forceinline__ ushort_t f2bf(float f) {
  union { float f; uint32_t u; } v; v.f = f;
  uint32_t u = v.u;
  uint32_t r = (u + 0x7FFFu + ((u >> 16) & 1u)) >> 16;  // RNE
  return (ushort_t)r;
}
// hardware packed bf16 convert (RNE): dst = {lo: bf16(a), hi: bf16(b)}
__device__ __forceinline__ uint32_t cvtpk(float a, float b) {
  uint32_t r;
  asm("v_cvt_pk_bf16_f32 %0, %1, %2" : "=v"(r) : "v"(a), "v"(b));
  return r;
}
__device__ __forceinline__ void gload_lds16(const void* g, void* l) {
  __builtin_amdgcn_global_load_lds(
      (const __attribute__((address_space(1))) void*)g,
      (__attribute__((address_space(3))) void*)l, 16, 0, 0);
}
// ds_read_b64_tr_b16 (cross-lane transpose): 16-lane group, lane reads its
// own qword at base+(l&15)*8; delivers column (l&15) of the [4kv][16d] subtile.
__device__ __forceinline__ void tr2(const ushort_t* p, bf16x4& lo, bf16x4& hi) {
  asm volatile("ds_read_b64_tr_b16 %0, %2\n\t"
               "ds_read_b64_tr_b16 %1, %2 offset:128"
               : "=&v"(lo), "=&v"(hi)
               : "v"((const __attribute__((address_space(3))) ushort_t*)p));
}

template <typename T> __device__ __forceinline__ T to_out(float f);
template <> __device__ __forceinline__ ushort_t to_out<ushort_t>(float f) { return f2bf(f); }
template <> __device__ __forceinline__ float to_out<float>(float f) { return f; }

#define SCQ 0.1803368801111204f   /* 0.125 * log2(e) */

// ---------------------------------------------------------------------------
// fp32 -> bf16 convert, three inputs, static block partition.
// 8 floats/thread: two float4 reads -> one 16B us8 store (G13 sweet spot).
// ---------------------------------------------------------------------------
__global__ void f2b3_kernel(const float* __restrict__ a, ushort_t* __restrict__ ao,
                            const float* __restrict__ b, ushort_t* __restrict__ bo,
                            const float* __restrict__ c, ushort_t* __restrict__ co) {
  int blk = blockIdx.x;
  const float* src; ushort_t* dst; int n8, b0, nb;
  if (blk < 1024)      { src = a; dst = ao; n8 = 524288; b0 = blk;        nb = 1024; }
  else if (blk < 1792) { src = b; dst = bo; n8 = 393216; b0 = blk - 1024; nb = 768; }
  else                 { src = c; dst = co; n8 = 131072; b0 = blk - 1792; nb = 256; }
  for (int i = b0 * 256 + threadIdx.x; i < n8; i += nb * 256) {
    float4 v0 = ((const float4*)src)[2 * i];
    float4 v1 = ((const float4*)src)[2 * i + 1];
    us8 o;
    o[0] = f2bf(v0.x); o[1] = f2bf(v0.y); o[2] = f2bf(v0.z); o[3] = f2bf(v0.w);
    o[4] = f2bf(v1.x); o[5] = f2bf(v1.y); o[6] = f2bf(v1.z); o[7] = f2bf(v1.w);
    ((us8*)dst)[i] = o;
  }
}

// ---------------------------------------------------------------------------
// GEMM: C[M][N] = A[M][K] @ W[N][K]^T (+bias), bf16 in, fp32 accum, OT out.
// SCALEQ: multiply output cols < 1024 by SCQ (Q-prescale for attn).
// T1 XCD swizzle: bijective blockIdx remap (nwg % 8 == 0).
// ---------------------------------------------------------------------------
template<bool BIAS, typename OT, bool SCALEQ>
__global__ __launch_bounds__(256, 2) void gemm_bt(
    const ushort_t* __restrict__ A, const ushort_t* __restrict__ W,
    const float* __restrict__ bias, OT* __restrict__ C,
    int M, int N, int K)
{
  __shared__ ushort_t As[128 * 64];
  __shared__ ushort_t Bs[128 * 64];
  const int t = threadIdx.x;
  const int w = t >> 6, lane = t & 63;
  const int lg = lane >> 4, lc = lane & 15;

  const int NX = N >> 7;
  const int nwg = gridDim.x;
  const int o = blockIdx.x;
  const int id = (o & 7) * (nwg >> 3) + (o >> 3);
  const int rowbase = (id / NX) * 128;
  const int colbase = (id % NX) * 128;
  const int wr = (w >> 1) * 64, wc = (w & 1) * 64;

  f32x4 acc[4][4] = {};
  const int nkt = K >> 6;

  for (int kt = 0; kt < nkt; ++kt) {
#pragma unroll
    for (int i = 0; i < 4; ++i) {
      int off = (i * 256 + t) * 16;
      int row = off >> 7;
      int cb  = off & 127;
      int ec  = cb ^ ((row & 7) << 4);
      gload_lds16(A + (size_t)(rowbase + row) * K + kt * 64 + (ec >> 1),
                  (char*)As + off);
      gload_lds16(W + (size_t)(colbase + row) * K + kt * 64 + (ec >> 1),
                  (char*)Bs + off);
    }
    __syncthreads();
#pragma unroll
    for (int kk = 0; kk < 2; ++kk) {
      bf16x8 af[4], bf[4];
#pragma unroll
      for (int m = 0; m < 4; ++m) {
        int row = wr + m * 16 + lc;
        int kb  = (lg * 16 + kk * 64) ^ ((row & 7) << 4);
        af[m] = *(const bf16x8*)((const char*)As + row * 128 + kb);
        int col = wc + m * 16 + lc;
        int kb2 = (lg * 16 + kk * 64) ^ ((col & 7) << 4);
        bf[m] = *(const bf16x8*)((const char*)Bs + col * 128 + kb2);
      }
#pragma unroll
      for (int m = 0; m < 4; ++m)
#pragma unroll
        for (int n = 0; n < 4; ++n)
          acc[m][n] = __builtin_amdgcn_mfma_f32_16x16x32_bf16(af[m], bf[n],
                                                              acc[m][n], 0, 0, 0);
    }
    __syncthreads();
  }

#pragma unroll
  for (int m = 0; m < 4; ++m) {
    int r0 = rowbase + wr + m * 16 + lg * 4;
#pragma unroll
    for (int n = 0; n < 4; ++n) {
      int c0 = colbase + wc + n * 16 + lc;
      float bv = 0.f;
      if (BIAS) bv = bias[c0];
      float qs = 1.f;
      if (SCALEQ) qs = (c0 < 1024) ? SCQ : 1.f;
#pragma unroll
      for (int j = 0; j < 4; ++j)
        C[(size_t)(r0 + j) * N + c0] = to_out<OT>(acc[m][n][j] * qs + bv);
    }
  }
}

// ---------------------------------------------------------------------------
// Flash attention (r14, verified best): 8 waves/512 thr, q-tile 256,
// KV-split(2), 16 iters kv64, max-free softmax (Q pre-scaled by SCQ),
// cvt_pk P-pack, permlane32_swap, tr_read V, MFMA-ones l row-sum.
// ---------------------------------------------------------------------------
__global__ __launch_bounds__(512, 4) void attn_fwd(
    const ushort_t* __restrict__ qkv, ushort_t* __restrict__ o1,
    ushort_t* __restrict__ o2, float* __restrict__ lbuf)
{
  __shared__ ushort_t Ks[2][64 * 64];
  __shared__ ushort_t Vs[2][64 * 64];

  const int t = threadIdx.x, w = t >> 6, lane = t & 63;
  const int l31 = lane & 31, hi = lane >> 5;
  const int lc = lane & 15;

  const int d = blockIdx.x;
  const int qt = (d >> 3) & 7;
  const int bhs = (d & 7) * 8 + (d >> 6);
  const int bh = bhs >> 1, split = bhs & 1;
  const int b = bh >> 4, h = bh & 15;

  const ushort_t* Qg = qkv + (size_t)(b * 2048) * 3072 + h * 64;
  const ushort_t* Kg = Qg + 1024 + (size_t)split * 1024 * 3072;
  const ushort_t* Vg = Qg + 2048 + (size_t)split * 1024 * 3072;

  auto stage_k = [&](ushort_t* Kd, int kt) {
    int off = t * 16;
    int row = off >> 7;
    int cb  = off & 127;
    int ec  = cb ^ ((row & 7) << 4);
    gload_lds16(Kg + (size_t)(kt * 64 + row) * 3072 + (ec >> 1),
                (char*)Kd + off);
  };
  const int vr  = t >> 3;
  const int vc0 = (t & 7) * 8;
  const int vdst = (vc0 >> 4) * 2048 + (vr >> 2) * 128 + (vr & 3) * 32 +
                   (vc0 & 8) * 2;

  const ushort_t* qrow_p = Qg + (size_t)(qt * 256 + w * 32 + l31) * 3072;
  bf16x8 qf[4];
#pragma unroll
  for (int kk = 0; kk < 4; ++kk)
    qf[kk] = *(const bf16x8*)(qrow_p + kk * 16 + hi * 8);

  bf16x8 ones;
#pragma unroll
  for (int i = 0; i < 8; ++i) ones[i] = (__bf16)1.0f;

  stage_k(Ks[0], 0);
  {
    us8 v = *(const us8*)(Vg + (size_t)vr * 3072 + vc0);
    *(us8*)((char*)Vs[0] + vdst) = v;
  }
  __syncthreads();

  f32x16 oacc0 = {}, oacc1 = {}, lacc = {};
  const int m16 = (lane >> 4) & 1;

  int cur = 0;
  for (int kt = 0; kt < 16; ++kt) {
    us8 vnext;
    if (kt < 15) {
      stage_k(Ks[cur ^ 1], kt + 1);
      vnext = *(const us8*)(Vg + (size_t)((kt + 1) * 64 + vr) * 3072 + vc0);
    }

    const ushort_t* Kc = Ks[cur];
    f32x16 s0 = {}, s1 = {};
    __builtin_amdgcn_s_setprio(1);
#pragma unroll
    for (int kk = 0; kk < 4; ++kk) {
      int cbyte = (kk * 32 + hi * 16);
      int r0 = l31, r1 = 32 + l31;
      bf16x8 kf0 = *(const bf16x8*)((const char*)Kc + r0 * 128 +
                                    (cbyte ^ ((r0 & 7) << 4)));
      bf16x8 kf1 = *(const bf16x8*)((const char*)Kc + r1 * 128 +
                                    (cbyte ^ ((r1 & 7) << 4)));
      s0 = __builtin_amdgcn_mfma_f32_32x32x16_bf16(kf0, qf[kk], s0, 0, 0, 0);
      s1 = __builtin_amdgcn_mfma_f32_32x32x16_bf16(kf1, qf[kk], s1, 0, 0, 0);
    }
    __builtin_amdgcn_s_setprio(0);

#pragma unroll
    for (int i = 0; i < 16; ++i) {
      s0[i] = __builtin_amdgcn_exp2f(s0[i]);
      s1[i] = __builtin_amdgcn_exp2f(s1[i]);
    }

    uint32_t pk0[8], pk1[8];
#pragma unroll
    for (int j = 0; j < 8; ++j) {
      pk0[j] = cvtpk(s0[2 * j], s0[2 * j + 1]);
      pk1[j] = cvtpk(s1[2 * j], s1[2 * j + 1]);
    }

    if (kt < 15)
      *(us8*)((char*)Vs[cur ^ 1] + vdst) = vnext;

    const ushort_t* Vc = Vs[cur];
    bf16x8 pa[4], vf[4][2];
#pragma unroll
    for (int ks = 0; ks < 4; ++ks) {
      int j0 = 4 * (ks & 1);
      uint32_t x0 = (ks < 2) ? pk0[j0]     : pk1[j0];
      uint32_t x1 = (ks < 2) ? pk0[j0 + 1] : pk1[j0 + 1];
      uint32_t y0 = (ks < 2) ? pk0[j0 + 2] : pk1[j0 + 2];
      uint32_t y1 = (ks < 2) ? pk0[j0 + 3] : pk1[j0 + 3];
      asm volatile("v_permlane32_swap_b32 %0, %1" : "+v"(x0), "+v"(y0));
      asm volatile("v_permlane32_swap_b32 %0, %1" : "+v"(x1), "+v"(y1));
      union { uint32_t du[4]; bf16x8 v; } U;
      U.du[0] = x0; U.du[1] = x1; U.du[2] = y0; U.du[3] = y1;
      pa[ks] = U.v;
#pragma unroll
      for (int nd = 0; nd < 2; ++nd) {
        bf16x4 lo, hh;
        tr2(Vc + (nd * 2 + m16) * 1024 + (4 * ks + 2 * hi) * 64 + lc * 4, lo, hh);
        vf[ks][nd] = __builtin_shufflevector(lo, hh, 0, 1, 2, 3, 4, 5, 6, 7);
      }
    }
    asm volatile("s_waitcnt lgkmcnt(0)" ::: "memory");  // rule #18
    __builtin_amdgcn_sched_barrier(0);
    __builtin_amdgcn_s_setprio(1);
#pragma unroll
    for (int ks = 0; ks < 4; ++ks) {
      oacc0 = __builtin_amdgcn_mfma_f32_32x32x16_bf16(pa[ks], vf[ks][0], oacc0, 0, 0, 0);
      oacc1 = __builtin_amdgcn_mfma_f32_32x32x16_bf16(pa[ks], vf[ks][1], oacc1, 0, 0, 0);
      lacc  = __builtin_amdgcn_mfma_f32_32x32x16_bf16(pa[ks], ones, lacc, 0, 0, 0);
    }
    __builtin_amdgcn_s_setprio(0);

    __syncthreads();
    cur ^= 1;
  }

  ushort_t* op = split ? o2 : o1;
  const int qrow0 = qt * 256 + w * 32;
#pragma unroll
  for (int r = 0; r < 16; ++r) {
    int crow = (r & 3) + 8 * (r >> 2) + 4 * hi;
    size_t base = ((size_t)(b * 2048 + qrow0 + crow)) * 1024 + h * 64 + l31;
    op[base]      = f2bf(oacc0[r]);
    op[base + 32] = f2bf(oacc1[r]);
  }
  if (l31 == 0) {
#pragma unroll
    for (int r = 0; r < 16; ++r) {
      int crow = (r & 3) + 8 * (r >> 2) + 4 * hi;
      lbuf[(size_t)split * 65536 +
           (size_t)(b * 2048 + qrow0 + crow) * 16 + h] = lacc[r];
    }
  }
}

// ---------------------------------------------------------------------------
// merge: o1 = (o1 + o2) / (l1 + l2), in-place (max-free partials).
// ---------------------------------------------------------------------------
__global__ void merge_kernel(ushort_t* __restrict__ o1,
                             const ushort_t* __restrict__ o2,
                             const float* __restrict__ lbuf) {
  int i = blockIdx.x * blockDim.x + threadIdx.x;
  int row = i >> 7;
  int col = (i & 127) * 8;
  int h = col >> 6;
  float l1 = lbuf[(size_t)row * 16 + h];
  float l2 = lbuf[65536 + (size_t)row * 16 + h];
  float inv = 1.f / (l1 + l2);
  us8 v1 = ((const us8*)o1)[i];
  us8 v2 = ((const us8*)o2)[i];
  us8 o;
#pragma unroll
  for (int j = 0; j < 8; ++j)
    o[j] = f2bf((bf2f(v1[j]) + bf2f(v2[j])) * inv);
  ((us8*)o1)[i] = o;
}

// ---------------------------------------------------------------------------
extern "C" void kernel_launch(void* const* d_in, const int* in_sizes, int n_in,
                              void* d_out, int out_size, void* d_ws, size_t ws_size,
                              hipStream_t stream) {
  const float* x     = (const float*)d_in[0];   // [2,2048,1024] fp32
  const float* Wqkv  = (const float*)d_in[1];   // [3072,1024] fp32
  const float* Wproj = (const float*)d_in[2];   // [1024,1024] fp32
  const float* bproj = (const float*)d_in[3];   // [1024] fp32
  float* out = (float*)d_out;                   // [4096,1024] fp32

  ushort_t* qkv   = (ushort_t*)d_ws;                    // [4096,3072] bf16
  ushort_t* o1    = qkv   + (size_t)4096 * 3072;        // [4096,1024] bf16 (O1/merged)
  ushort_t* xb    = o1    + (size_t)4096 * 1024;        // [4096,1024] bf16 (x, then O2)
  ushort_t* wqb   = xb    + (size_t)4096 * 1024;        // [3072,1024] bf16
  ushort_t* wpb   = wqb   + (size_t)3072 * 1024;        // [1024,1024] bf16
  float*    lbuf  = (float*)(wpb + (size_t)1024 * 1024); // [2][4096][16] float

  dim3 blk(256);
  f2b3_kernel<<<2048, blk, 0, stream>>>(x, xb, Wqkv, wqb, Wproj, wpb);

  gemm_bt<false, ushort_t, true><<<768, blk, 0, stream>>>(
      xb, wqb, nullptr, qkv, 4096, 3072, 1024);
  attn_fwd<<<dim3(512), dim3(512), 0, stream>>>(qkv, o1, xb, lbuf);
  merge_kernel<<<2048, blk, 0, stream>>>(o1, xb, lbuf);
  gemm_bt<true, float, false><<<256, blk, 0, stream>>>(
      o1, wpb, bproj, out, 4096, 1024, 1024);
}

// Round 19
// 109.120 us; speedup vs baseline: 1.0599x; 1.0042x over previous
//
#include <hip/hip_runtime.h>
#include <stdint.h>

typedef unsigned short ushort_t;
typedef __bf16 bf16x4 __attribute__((ext_vector_type(4)));
typedef __bf16 bf16x8 __attribute__((ext_vector_type(8)));
typedef float f32x4 __attribute__((ext_vector_type(4)));
typedef float f32x16 __attribute__((ext_vector_type(16)));
typedef unsigned short us8 __attribute__((ext_vector_type(8)));
typedef unsigned short us4v __attribute__((ext_vector_type(4)));

__device__ __forceinline__ float bf2f(ushort_t u) {
  union { uint32_t u; float f; } v; v.u = ((uint32_t)u) << 16; return v.f;
}
__device__ __forceinline__ ushort_t f2bf(float f) {
  union { float f; uint32_t u; } v; v.f = f;
  uint32_t u = v.u;
  uint32_t r = (u + 0x7FFFu + ((u >> 16) & 1u)) >> 16;  // RNE
  return (ushort_t)r;
}
// hardware packed bf16 convert (RNE): dst = {lo: bf16(a), hi: bf16(b)}
__device__ __forceinline__ uint32_t cvtpk(float a, float b) {
  uint32_t r;
  asm("v_cvt_pk_bf16_f32 %0, %1, %2" : "=v"(r) : "v"(a), "v"(b));
  return r;
}
__device__ __forceinline__ void gload_lds16(const void* g, void* l) {
  __builtin_amdgcn_global_load_lds(
      (const __attribute__((address_space(1))) void*)g,
      (__attribute__((address_space(3))) void*)l, 16, 0, 0);
}
// ds_read_b64_tr_b16 (cross-lane transpose): 16-lane group, lane reads its
// own qword at base+(l&15)*8; delivers column (l&15) of the [4kv][16d] subtile.
__device__ __forceinline__ void tr2(const ushort_t* p, bf16x4& lo, bf16x4& hi) {
  asm volatile("ds_read_b64_tr_b16 %0, %2\n\t"
               "ds_read_b64_tr_b16 %1, %2 offset:128"
               : "=&v"(lo), "=&v"(hi)
               : "v"((const __attribute__((address_space(3))) ushort_t*)p));
}

template <typename T> __device__ __forceinline__ T to_out(float f);
template <> __device__ __forceinline__ ushort_t to_out<ushort_t>(float f) { return f2bf(f); }
template <> __device__ __forceinline__ float to_out<float>(float f) { return f; }

#define SCQ 0.1803368801111204f   /* 0.125 * log2(e) */

// ---------------------------------------------------------------------------
// fp32 -> bf16 convert, three inputs, static block partition
// ---------------------------------------------------------------------------
__global__ void f2b3_kernel(const float* __restrict__ a, ushort_t* __restrict__ ao,
                            const float* __restrict__ b, ushort_t* __restrict__ bo,
                            const float* __restrict__ c, ushort_t* __restrict__ co) {
  int blk = blockIdx.x;
  const float* src; ushort_t* dst; int n4, b0, nb;
  if (blk < 1024)      { src = a; dst = ao; n4 = 1048576; b0 = blk;        nb = 1024; }
  else if (blk < 1792) { src = b; dst = bo; n4 = 786432;  b0 = blk - 1024; nb = 768; }
  else                 { src = c; dst = co; n4 = 262144;  b0 = blk - 1792; nb = 256; }
  for (int i = b0 * 256 + threadIdx.x; i < n4; i += nb * 256) {
    float4 v = ((const float4*)src)[i];
    us4v o;
    o[0] = f2bf(v.x); o[1] = f2bf(v.y); o[2] = f2bf(v.z); o[3] = f2bf(v.w);
    ((us4v*)dst)[i] = o;
  }
}

// ---------------------------------------------------------------------------
// GEMM: C[M][N] = A[M][K] @ W[N][K]^T (+bias), bf16 in, fp32 accum, OT out.
// SCALEQ: multiply output cols < 1024 by SCQ (Q-prescale for attn).
// T1 XCD swizzle: bijective blockIdx remap (nwg % 8 == 0).
// ---------------------------------------------------------------------------
template<bool BIAS, typename OT, bool SCALEQ>
__global__ __launch_bounds__(256, 2) void gemm_bt(
    const ushort_t* __restrict__ A, const ushort_t* __restrict__ W,
    const float* __restrict__ bias, OT* __restrict__ C,
    int M, int N, int K)
{
  __shared__ ushort_t As[128 * 64];
  __shared__ ushort_t Bs[128 * 64];
  const int t = threadIdx.x;
  const int w = t >> 6, lane = t & 63;
  const int lg = lane >> 4, lc = lane & 15;

  const int NX = N >> 7;
  const int nwg = gridDim.x;
  const int o = blockIdx.x;
  const int id = (o & 7) * (nwg >> 3) + (o >> 3);
  const int rowbase = (id / NX) * 128;
  const int colbase = (id % NX) * 128;
  const int wr = (w >> 1) * 64, wc = (w & 1) * 64;

  f32x4 acc[4][4] = {};
  const int nkt = K >> 6;

  for (int kt = 0; kt < nkt; ++kt) {
#pragma unroll
    for (int i = 0; i < 4; ++i) {
      int off = (i * 256 + t) * 16;
      int row = off >> 7;
      int cb  = off & 127;
      int ec  = cb ^ ((row & 7) << 4);
      gload_lds16(A + (size_t)(rowbase + row) * K + kt * 64 + (ec >> 1),
                  (char*)As + off);
      gload_lds16(W + (size_t)(colbase + row) * K + kt * 64 + (ec >> 1),
                  (char*)Bs + off);
    }
    __syncthreads();
#pragma unroll
    for (int kk = 0; kk < 2; ++kk) {
      bf16x8 af[4], bf[4];
#pragma unroll
      for (int m = 0; m < 4; ++m) {
        int row = wr + m * 16 + lc;
        int kb  = (lg * 16 + kk * 64) ^ ((row & 7) << 4);
        af[m] = *(const bf16x8*)((const char*)As + row * 128 + kb);
        int col = wc + m * 16 + lc;
        int kb2 = (lg * 16 + kk * 64) ^ ((col & 7) << 4);
        bf[m] = *(const bf16x8*)((const char*)Bs + col * 128 + kb2);
      }
#pragma unroll
      for (int m = 0; m < 4; ++m)
#pragma unroll
        for (int n = 0; n < 4; ++n)
          acc[m][n] = __builtin_amdgcn_mfma_f32_16x16x32_bf16(af[m], bf[n],
                                                              acc[m][n], 0, 0, 0);
    }
    __syncthreads();
  }

#pragma unroll
  for (int m = 0; m < 4; ++m) {
    int r0 = rowbase + wr + m * 16 + lg * 4;
#pragma unroll
    for (int n = 0; n < 4; ++n) {
      int c0 = colbase + wc + n * 16 + lc;
      float bv = 0.f;
      if (BIAS) bv = bias[c0];
      float qs = 1.f;
      if (SCALEQ) qs = (c0 < 1024) ? SCQ : 1.f;
#pragma unroll
      for (int j = 0; j < 4; ++j)
        C[(size_t)(r0 + j) * N + c0] = to_out<OT>(acc[m][n][j] * qs + bv);
    }
  }
}

// ---------------------------------------------------------------------------
// Flash attention (r14, session best): 8 waves/512 thr, q-tile 256,
// KV-split(2), 16 iters kv64, max-free softmax (Q pre-scaled by SCQ),
// cvt_pk P-pack, permlane32_swap, tr_read V, MFMA-ones l row-sum.
// Partials unnormalized bf16 + l; merged by merge_kernel (L2-safe).
// ---------------------------------------------------------------------------
__global__ __launch_bounds__(512, 4) void attn_fwd(
    const ushort_t* __restrict__ qkv, ushort_t* __restrict__ o1,
    ushort_t* __restrict__ o2, float* __restrict__ lbuf)
{
  __shared__ ushort_t Ks[2][64 * 64];
  __shared__ ushort_t Vs[2][64 * 64];

  const int t = threadIdx.x, w = t >> 6, lane = t & 63;
  const int l31 = lane & 31, hi = lane >> 5;
  const int lc = lane & 15;

  // bijective decode: xcd = d&7, qt = (d>>3)&7, bhs = xcd*8 + (d>>6)
  const int d = blockIdx.x;
  const int qt = (d >> 3) & 7;
  const int bhs = (d & 7) * 8 + (d >> 6);
  const int bh = bhs >> 1, split = bhs & 1;
  const int b = bh >> 4, h = bh & 15;

  const ushort_t* Qg = qkv + (size_t)(b * 2048) * 3072 + h * 64;
  const ushort_t* Kg = Qg + 1024 + (size_t)split * 1024 * 3072;
  const ushort_t* Vg = Qg + 2048 + (size_t)split * 1024 * 3072;

  auto stage_k = [&](ushort_t* Kd, int kt) {
    int off = t * 16;
    int row = off >> 7;
    int cb  = off & 127;
    int ec  = cb ^ ((row & 7) << 4);
    gload_lds16(Kg + (size_t)(kt * 64 + row) * 3072 + (ec >> 1),
                (char*)Kd + off);
  };
  const int vr  = t >> 3;
  const int vc0 = (t & 7) * 8;
  const int vdst = (vc0 >> 4) * 2048 + (vr >> 2) * 128 + (vr & 3) * 32 +
                   (vc0 & 8) * 2;

  // ---- Q fragments (B-operand): lane -> Q[q=l31][d = kk*16+hi*8+e] ----
  const ushort_t* qrow_p = Qg + (size_t)(qt * 256 + w * 32 + l31) * 3072;
  bf16x8 qf[4];
#pragma unroll
  for (int kk = 0; kk < 4; ++kk)
    qf[kk] = *(const bf16x8*)(qrow_p + kk * 16 + hi * 8);

  // ---- all-ones B fragment for the MFMA row-sum ----
  bf16x8 ones;
#pragma unroll
  for (int i = 0; i < 8; ++i) ones[i] = (__bf16)1.0f;

  // ---- prologue staging ----
  stage_k(Ks[0], 0);
  {
    us8 v = *(const us8*)(Vg + (size_t)vr * 3072 + vc0);
    *(us8*)((char*)Vs[0] + vdst) = v;
  }
  __syncthreads();

  f32x16 oacc0 = {}, oacc1 = {}, lacc = {};
  const int m16 = (lane >> 4) & 1;

  int cur = 0;
  for (int kt = 0; kt < 16; ++kt) {
    // ---- issue next tile's loads early ----
    us8 vnext;
    if (kt < 15) {
      stage_k(Ks[cur ^ 1], kt + 1);
      vnext = *(const us8*)(Vg + (size_t)((kt + 1) * 64 + vr) * 3072 + vc0);
    }

    // ---- S^T = K @ Q'^T (Q pre-scaled by SCQ) ----
    const ushort_t* Kc = Ks[cur];
    f32x16 s0 = {}, s1 = {};
    __builtin_amdgcn_s_setprio(1);
#pragma unroll
    for (int kk = 0; kk < 4; ++kk) {
      int cbyte = (kk * 32 + hi * 16);
      int r0 = l31, r1 = 32 + l31;
      bf16x8 kf0 = *(const bf16x8*)((const char*)Kc + r0 * 128 +
                                    (cbyte ^ ((r0 & 7) << 4)));
      bf16x8 kf1 = *(const bf16x8*)((const char*)Kc + r1 * 128 +
                                    (cbyte ^ ((r1 & 7) << 4)));
      s0 = __builtin_amdgcn_mfma_f32_32x32x16_bf16(kf0, qf[kk], s0, 0, 0, 0);
      s1 = __builtin_amdgcn_mfma_f32_32x32x16_bf16(kf1, qf[kk], s1, 0, 0, 0);
    }
    __builtin_amdgcn_s_setprio(0);

    // ---- max-free softmax: P = exp2(s) (bounded; Q carries the scale) ----
#pragma unroll
    for (int i = 0; i < 16; ++i) {
      s0[i] = __builtin_amdgcn_exp2f(s0[i]);
      s1[i] = __builtin_amdgcn_exp2f(s1[i]);
    }

    // ---- P -> bf16 dwords via hardware cvt_pk (pairs of consecutive r) ----
    uint32_t pk0[8], pk1[8];
#pragma unroll
    for (int j = 0; j < 8; ++j) {
      pk0[j] = cvtpk(s0[2 * j], s0[2 * j + 1]);
      pk1[j] = cvtpk(s1[2 * j], s1[2 * j + 1]);
    }

    // ---- write next V tile ----
    if (kt < 15)
      *(us8*)((char*)Vs[cur ^ 1] + vdst) = vnext;

    // ---- build PV operands: pa via permlane32_swap, vf via tr_read ----
    const ushort_t* Vc = Vs[cur];
    bf16x8 pa[4], vf[4][2];
#pragma unroll
    for (int ks = 0; ks < 4; ++ks) {
      int j0 = 4 * (ks & 1);
      uint32_t x0 = (ks < 2) ? pk0[j0]     : pk1[j0];
      uint32_t x1 = (ks < 2) ? pk0[j0 + 1] : pk1[j0 + 1];
      uint32_t y0 = (ks < 2) ? pk0[j0 + 2] : pk1[j0 + 2];
      uint32_t y1 = (ks < 2) ? pk0[j0 + 3] : pk1[j0 + 3];
      asm volatile("v_permlane32_swap_b32 %0, %1" : "+v"(x0), "+v"(y0));
      asm volatile("v_permlane32_swap_b32 %0, %1" : "+v"(x1), "+v"(y1));
      union { uint32_t du[4]; bf16x8 v; } U;
      U.du[0] = x0; U.du[1] = x1; U.du[2] = y0; U.du[3] = y1;
      pa[ks] = U.v;
#pragma unroll
      for (int nd = 0; nd < 2; ++nd) {
        bf16x4 lo, hh;
        tr2(Vc + (nd * 2 + m16) * 1024 + (4 * ks + 2 * hi) * 64 + lc * 4, lo, hh);
        vf[ks][nd] = __builtin_shufflevector(lo, hh, 0, 1, 2, 3, 4, 5, 6, 7);
      }
    }
    asm volatile("s_waitcnt lgkmcnt(0)" ::: "memory");  // rule #18
    __builtin_amdgcn_sched_barrier(0);
    __builtin_amdgcn_s_setprio(1);
#pragma unroll
    for (int ks = 0; ks < 4; ++ks) {
      oacc0 = __builtin_amdgcn_mfma_f32_32x32x16_bf16(pa[ks], vf[ks][0], oacc0, 0, 0, 0);
      oacc1 = __builtin_amdgcn_mfma_f32_32x32x16_bf16(pa[ks], vf[ks][1], oacc1, 0, 0, 0);
      lacc  = __builtin_amdgcn_mfma_f32_32x32x16_bf16(pa[ks], ones, lacc, 0, 0, 0);
    }
    __builtin_amdgcn_s_setprio(0);

    __syncthreads();
    cur ^= 1;
  }

  // ---- epilogue: unnormalized partial O + row-sum l (from lacc) ----
  ushort_t* op = split ? o2 : o1;
  const int qrow0 = qt * 256 + w * 32;
#pragma unroll
  for (int r = 0; r < 16; ++r) {
    int crow = (r & 3) + 8 * (r >> 2) + 4 * hi;
    size_t base = ((size_t)(b * 2048 + qrow0 + crow)) * 1024 + h * 64 + l31;
    op[base]      = f2bf(oacc0[r]);
    op[base + 32] = f2bf(oacc1[r]);
  }
  // lacc[r] = l[q=crow(r,hi)], replicated across all 32 columns (l31)
  if (l31 == 0) {
#pragma unroll
    for (int r = 0; r < 16; ++r) {
      int crow = (r & 3) + 8 * (r >> 2) + 4 * hi;
      lbuf[(size_t)split * 65536 +
           (size_t)(b * 2048 + qrow0 + crow) * 16 + h] = lacc[r];
    }
  }
}

// ---------------------------------------------------------------------------
// merge: o1 = (o1 + o2) / (l1 + l2), in-place (max-free partials).
// ---------------------------------------------------------------------------
__global__ void merge_kernel(ushort_t* __restrict__ o1,
                             const ushort_t* __restrict__ o2,
                             const float* __restrict__ lbuf) {
  int i = blockIdx.x * blockDim.x + threadIdx.x;
  int row = i >> 7;
  int col = (i & 127) * 8;
  int h = col >> 6;
  float l1 = lbuf[(size_t)row * 16 + h];
  float l2 = lbuf[65536 + (size_t)row * 16 + h];
  float inv = 1.f / (l1 + l2);
  us8 v1 = ((const us8*)o1)[i];
  us8 v2 = ((const us8*)o2)[i];
  us8 o;
#pragma unroll
  for (int j = 0; j < 8; ++j)
    o[j] = f2bf((bf2f(v1[j]) + bf2f(v2[j])) * inv);
  ((us8*)o1)[i] = o;
}

// ---------------------------------------------------------------------------
extern "C" void kernel_launch(void* const* d_in, const int* in_sizes, int n_in,
                              void* d_out, int out_size, void* d_ws, size_t ws_size,
                              hipStream_t stream) {
  const float* x     = (const float*)d_in[0];   // [2,2048,1024] fp32
  const float* Wqkv  = (const float*)d_in[1];   // [3072,1024] fp32
  const float* Wproj = (const float*)d_in[2];   // [1024,1024] fp32
  const float* bproj = (const float*)d_in[3];   // [1024] fp32
  float* out = (float*)d_out;                   // [4096,1024] fp32

  ushort_t* qkv   = (ushort_t*)d_ws;                    // [4096,3072] bf16
  ushort_t* o1    = qkv   + (size_t)4096 * 3072;        // [4096,1024] bf16 (O1/merged)
  ushort_t* xb    = o1    + (size_t)4096 * 1024;        // [4096,1024] bf16 (x, then O2)
  ushort_t* wqb   = xb    + (size_t)4096 * 1024;        // [3072,1024] bf16
  ushort_t* wpb   = wqb   + (size_t)3072 * 1024;        // [1024,1024] bf16
  float*    lbuf  = (float*)(wpb + (size_t)1024 * 1024); // [2][4096][16] float

  dim3 blk(256);
  f2b3_kernel<<<2048, blk, 0, stream>>>(x, xb, Wqkv, wqb, Wproj, wpb);

  gemm_bt<false, ushort_t, true><<<768, blk, 0, stream>>>(
      xb, wqb, nullptr, qkv, 4096, 3072, 1024);
  attn_fwd<<<dim3(512), dim3(512), 0, stream>>>(qkv, o1, xb, lbuf);
  merge_kernel<<<2048, blk, 0, stream>>>(o1, xb, lbuf);
  gemm_bt<true, float, false><<<256, blk, 0, stream>>>(
      o1, wpb, bproj, out, 4096, 1024, 1024);
}